// Round 1
// baseline (3430.188 us; speedup 1.0000x reference)
//
#include <hip/hip_runtime.h>

#define T_TOK 8192   // B*S tokens
#define HDIM  2048
#define IDIM  8192
#define KKEEP 4096

typedef _Float16 f16x8 __attribute__((ext_vector_type(8)));
typedef float    f32x4 __attribute__((ext_vector_type(4)));

// ---------------- cast kernels ----------------

// x -> f16 hi, plus lo residual scaled by 2^11 (keeps lo in f16 normal range)
__global__ void cast_split(const float4* __restrict__ in, ushort4* __restrict__ hi,
                           ushort4* __restrict__ lo2, long n4) {
    long stride = (long)gridDim.x * blockDim.x;
    for (long i = (long)blockIdx.x * blockDim.x + threadIdx.x; i < n4; i += stride) {
        float4 v = in[i];
        float vv[4] = {v.x, v.y, v.z, v.w};
        union { _Float16 f[4]; ushort4 u; } H, L;
        #pragma unroll
        for (int j = 0; j < 4; ++j) {
            _Float16 h = (_Float16)vv[j];
            H.f[j] = h;
            L.f[j] = (_Float16)((vv[j] - (float)h) * 2048.0f);
        }
        hi[i] = H.u;
        lo2[i] = L.u;
    }
}

__global__ void cast_f16(const float4* __restrict__ in, ushort4* __restrict__ o, long n4) {
    long stride = (long)gridDim.x * blockDim.x;
    for (long i = (long)blockIdx.x * blockDim.x + threadIdx.x; i < n4; i += stride) {
        float4 v = in[i];
        float vv[4] = {v.x, v.y, v.z, v.w};
        union { _Float16 f[4]; ushort4 u; } H;
        #pragma unroll
        for (int j = 0; j < 4; ++j) H.f[j] = (_Float16)vv[j];
        o[i] = H.u;
    }
}

// ---------------- GEMM (NT: A[M,K] row-major, B[N,K] row-major, C[M,N]) ----------------
// m97-style structure: 128x128 tile, BK=32, 4 waves (each 64x64), 16x16x32 f16 MFMA,
// global_load_lds width 16.  EPI=0: C = beta*C + scale*acc (f32).
// EPI=1: P[idx] = (|gate[idx]| >= kth[row]) ? gate[idx]*acc : 0   (f16)

template <int EPI>
__global__ __launch_bounds__(256) void gemm_nt_f16(
    const _Float16* __restrict__ A0, const _Float16* __restrict__ B0,
    const _Float16* __restrict__ A1, const _Float16* __restrict__ B1,
    int nPairs, int N, int Kp,
    float* __restrict__ Cf, float scale, int beta,
    const float* __restrict__ gate, const float* __restrict__ kth,
    _Float16* __restrict__ P)
{
    __shared__ _Float16 As[128 * 32];
    __shared__ _Float16 Bs[128 * 32];
    const int tid  = threadIdx.x;
    const int lane = tid & 63;
    const int wave = tid >> 6;
    const int bm = blockIdx.x, bn = blockIdx.y;
    const int wr = wave >> 1, wc = wave & 1;

    f32x4 acc[4][4] = {};

    // staging: 2 sweeps; wave-uniform LDS dest, per-lane global src
    const int srow = wave * 16 + (lane >> 2);   // row within 64-row sweep
    const int scol = (lane & 3) * 8;            // 8-elem (16B) column chunk
    const int lrow = lane & 15;
    const int lk   = (lane >> 4) * 8;

    for (int p = 0; p < nPairs; ++p) {
        const _Float16* Ap = p ? A1 : A0;
        const _Float16* Bp = p ? B1 : B0;
        const _Float16* Ab = Ap + (size_t)bm * 128 * Kp;
        const _Float16* Bb = Bp + (size_t)bn * 128 * Kp;
        for (int kt = 0; kt < Kp; kt += 32) {
            if (p | kt) __syncthreads();
            #pragma unroll
            for (int s = 0; s < 2; ++s) {
                const _Float16* ga = Ab + (size_t)(s * 64 + srow) * Kp + (kt + scol);
                const _Float16* gb = Bb + (size_t)(s * 64 + srow) * Kp + (kt + scol);
                __builtin_amdgcn_global_load_lds(
                    (const __attribute__((address_space(1))) void*)ga,
                    (__attribute__((address_space(3))) void*)(As + s * 2048 + wave * 512),
                    16, 0, 0);
                __builtin_amdgcn_global_load_lds(
                    (const __attribute__((address_space(1))) void*)gb,
                    (__attribute__((address_space(3))) void*)(Bs + s * 2048 + wave * 512),
                    16, 0, 0);
            }
            __syncthreads();
            f16x8 af[4], bf[4];
            #pragma unroll
            for (int m = 0; m < 4; ++m)
                af[m] = *(const f16x8*)(As + (wr * 64 + m * 16 + lrow) * 32 + lk);
            #pragma unroll
            for (int n = 0; n < 4; ++n)
                bf[n] = *(const f16x8*)(Bs + (wc * 64 + n * 16 + lrow) * 32 + lk);
            #pragma unroll
            for (int m = 0; m < 4; ++m)
                #pragma unroll
                for (int n = 0; n < 4; ++n)
                    acc[m][n] = __builtin_amdgcn_mfma_f32_16x16x32_f16(af[m], bf[n], acc[m][n], 0, 0, 0);
        }
    }

    // epilogue; C/D layout: col = lane&15, row = (lane>>4)*4 + reg
    const int r0 = bm * 128 + wr * 64 + (lane >> 4) * 4;
    const int c0 = bn * 128 + wc * 64 + (lane & 15);
    #pragma unroll
    for (int m = 0; m < 4; ++m) {
        #pragma unroll
        for (int n = 0; n < 4; ++n) {
            #pragma unroll
            for (int r = 0; r < 4; ++r) {
                const int row = r0 + m * 16 + r;
                const int col = c0 + n * 16;
                const size_t idx = (size_t)row * N + col;
                if (EPI == 0) {
                    float v = scale * acc[m][n][r];
                    Cf[idx] = beta ? (Cf[idx] + v) : v;
                } else {
                    float g = gate[idx];
                    float pv = (fabsf(g) >= kth[row]) ? g * acc[m][n][r] : 0.0f;
                    P[idx] = (_Float16)pv;
                }
            }
        }
    }
}

// ---------------- exact K-th largest |gate| per token (radix select, 4x8-bit) ----------------

__global__ __launch_bounds__(256) void topk_kth(const float* __restrict__ gate,
                                                float* __restrict__ kth) {
    __shared__ unsigned keys[IDIM];
    __shared__ unsigned hist[256];
    __shared__ unsigned sA[256], sB[256];
    __shared__ unsigned selBin, selAbove;

    const int tid = threadIdx.x;
    const int t = blockIdx.x;
    const float* row = gate + (size_t)t * IDIM;

    for (int j = tid; j < IDIM; j += 256)
        keys[j] = __float_as_uint(fabsf(row[j]));   // |g| >= 0: uint order == float order
    __syncthreads();

    unsigned prefix = 0;
    int Krem = KKEEP;
    for (int pass = 0; pass < 4; ++pass) {
        const int shift = 24 - 8 * pass;
        hist[tid] = 0;
        __syncthreads();
        for (int j = tid; j < IDIM; j += 256) {
            unsigned k = keys[j];
            bool ok = (pass == 0) || (((k ^ prefix) >> (shift + 8)) == 0u);
            if (ok) atomicAdd(&hist[(k >> shift) & 255u], 1u);
        }
        __syncthreads();
        // suffix sums S(b) = count of matching keys with byte >= b
        sA[tid] = hist[tid];
        __syncthreads();
        unsigned* src = sA; unsigned* dst = sB;
        for (int off = 1; off < 256; off <<= 1) {
            unsigned v = src[tid] + ((tid + off < 256) ? src[tid + off] : 0u);
            dst[tid] = v;
            __syncthreads();
            unsigned* tmp = src; src = dst; dst = tmp;
        }
        unsigned S  = src[tid];
        unsigned Sn = (tid < 255) ? src[tid + 1] : 0u;
        if ((int)S >= Krem && (int)Sn < Krem) { selBin = (unsigned)tid; selAbove = Sn; }
        __syncthreads();
        prefix |= (selBin << shift);
        Krem -= (int)selAbove;
        __syncthreads();
    }
    if (tid == 0) kth[t] = __uint_as_float(prefix);
}

// ---------------- host ----------------

extern "C" void kernel_launch(void* const* d_in, const int* in_sizes, int n_in,
                              void* d_out, int out_size, void* d_ws, size_t ws_size,
                              hipStream_t stream) {
    const float* x  = (const float*)d_in[0];   // [T,H]
    const float* Wg = (const float*)d_in[1];   // [I,H]
    const float* Wu = (const float*)d_in[2];   // [I,H]
    const float* Wd = (const float*)d_in[3];   // [H,I]
    float* out = (float*)d_out;                // [T,H]

    const size_t NE = (size_t)T_TOK * HDIM;    // 16.8M == I*H == H*I
    char* ws = (char*)d_ws;
    _Float16* xh   = (_Float16*)(ws + 0 * NE);
    _Float16* xl2  = (_Float16*)(ws + 2 * NE);
    _Float16* Wgh  = (_Float16*)(ws + 4 * NE);
    _Float16* Wgl2 = (_Float16*)(ws + 6 * NE);
    _Float16* Wu16 = (_Float16*)(ws + 8 * NE);
    _Float16* Wd16 = (_Float16*)(ws + 10 * NE);
    char* dyn = ws + 12 * NE;

    // chunk tokens so gate(f32)+P(f16)+kth fit in remaining ws
    int Tc = T_TOK;
    while (Tc > 128) {
        size_t need = 12 * NE + (size_t)Tc * IDIM * 4 + (size_t)Tc * IDIM * 2 + (size_t)Tc * 4 + 256;
        if (need <= ws_size) break;
        Tc >>= 1;
    }
    float*    gate = (float*)dyn;
    _Float16* P    = (_Float16*)(dyn + (size_t)Tc * IDIM * 4);
    float*    kth  = (float*)(dyn + (size_t)Tc * IDIM * 4 + (size_t)Tc * IDIM * 2);

    const long n4 = (long)(NE / 4);
    cast_split<<<1024, 256, 0, stream>>>((const float4*)x,  (ushort4*)xh,  (ushort4*)xl2, n4);
    cast_split<<<1024, 256, 0, stream>>>((const float4*)Wg, (ushort4*)Wgh, (ushort4*)Wgl2, n4);
    cast_f16 <<<1024, 256, 0, stream>>>((const float4*)Wu, (ushort4*)Wu16, n4);
    cast_f16 <<<1024, 256, 0, stream>>>((const float4*)Wd, (ushort4*)Wd16, n4);

    for (int c0 = 0; c0 < T_TOK; c0 += Tc) {
        const _Float16* xh_c  = xh  + (size_t)c0 * HDIM;
        const _Float16* xl2_c = xl2 + (size_t)c0 * HDIM;
        dim3 gI(Tc / 128, IDIM / 128);
        // G1: gate = xh @ Wgh^T   (f32)
        gemm_nt_f16<0><<<gI, 256, 0, stream>>>(xh_c, Wgh, nullptr, nullptr, 1, IDIM, HDIM,
                                               gate, 1.0f, 0, nullptr, nullptr, nullptr);
        // G2: gate += 2^-11 * (xl2 @ Wgh^T + xh @ Wgl2^T)
        gemm_nt_f16<0><<<gI, 256, 0, stream>>>(xl2_c, Wgh, xh_c, Wgl2, 2, IDIM, HDIM,
                                               gate, 1.0f / 2048.0f, 1, nullptr, nullptr, nullptr);
        // exact kth per token
        topk_kth<<<Tc, 256, 0, stream>>>(gate, kth);
        // UP with fused top-k mask epilogue: P = (|g|>=kth) ? g*u : 0  (f16)
        gemm_nt_f16<1><<<gI, 256, 0, stream>>>(xh_c, Wu16, nullptr, nullptr, 1, IDIM, HDIM,
                                               nullptr, 1.0f, 0, gate, kth, P);
        // DOWN: out = P @ Wd16^T  (f32)
        dim3 gD(Tc / 128, HDIM / 128);
        gemm_nt_f16<0><<<gD, 256, 0, stream>>>(P, Wd16, nullptr, nullptr, 1, HDIM, IDIM,
                                               out + (size_t)c0 * HDIM, 1.0f, 0, nullptr, nullptr, nullptr);
    }
}

// Round 2
// 2488.626 us; speedup vs baseline: 1.3783x; 1.3783x over previous
//
#include <hip/hip_runtime.h>

#define T_TOK 8192   // B*S tokens
#define HDIM  2048
#define IDIM  8192
#define KKEEP 4096

typedef _Float16 f16x8 __attribute__((ext_vector_type(8)));
typedef float    f32x4 __attribute__((ext_vector_type(4)));

// ---------------- cast kernels ----------------

__global__ void cast_split(const float4* __restrict__ in, ushort4* __restrict__ hi,
                           ushort4* __restrict__ lo2, long n4) {
    long stride = (long)gridDim.x * blockDim.x;
    for (long i = (long)blockIdx.x * blockDim.x + threadIdx.x; i < n4; i += stride) {
        float4 v = in[i];
        float vv[4] = {v.x, v.y, v.z, v.w};
        union { _Float16 f[4]; ushort4 u; } H, L;
        #pragma unroll
        for (int j = 0; j < 4; ++j) {
            _Float16 h = (_Float16)vv[j];
            H.f[j] = h;
            L.f[j] = (_Float16)((vv[j] - (float)h) * 2048.0f);
        }
        hi[i] = H.u;
        lo2[i] = L.u;
    }
}

__global__ void cast_f16(const float4* __restrict__ in, ushort4* __restrict__ o, long n4) {
    long stride = (long)gridDim.x * blockDim.x;
    for (long i = (long)blockIdx.x * blockDim.x + threadIdx.x; i < n4; i += stride) {
        float4 v = in[i];
        float vv[4] = {v.x, v.y, v.z, v.w};
        union { _Float16 f[4]; ushort4 u; } H;
        #pragma unroll
        for (int j = 0; j < 4; ++j) H.f[j] = (_Float16)vv[j];
        o[i] = H.u;
    }
}

// ---------------- GEMM (NT layout), m97 structure, XCD-swizzled ----------------
// MODE 0: DOWN  — C f32 = A@B^T
// MODE 1: UP    — in-place: GP[idx] = (f16)( (float)GP[idx] * acc )   (P = gmask * up)
// MODE 2: GATE  — 3 passes: acc = A0@B0^T + A1@B1^T; acc *= 2^-11; acc += A2@B2^T; C f32

template <int MODE>
__global__ __launch_bounds__(256) void gemm_k(
    const _Float16* __restrict__ A0, const _Float16* __restrict__ B0,
    const _Float16* __restrict__ A1, const _Float16* __restrict__ B1,
    const _Float16* __restrict__ A2, const _Float16* __restrict__ B2,
    int N, int Kp, float* __restrict__ Cf, _Float16* __restrict__ GP)
{
    __shared__ _Float16 As[128 * 32];
    __shared__ _Float16 Bs[128 * 32];
    const int tid  = threadIdx.x;
    const int lane = tid & 63;
    const int wave = tid >> 6;
    const int wr = wave >> 1, wc = wave & 1;

    // XCD-bijective swizzle of the flattened block id (8 XCDs)
    const int gx = gridDim.x, gy = gridDim.y;
    const int nwg = gx * gy;
    const int orig = blockIdx.y * gx + blockIdx.x;
    const int q = nwg >> 3, r = nwg & 7, xcd = orig & 7, lid = orig >> 3;
    const int wg = (xcd < r ? xcd * (q + 1) : r * (q + 1) + (xcd - r) * q) + lid;
    const int bm = wg / gy, bn = wg % gy;

    f32x4 acc[4][4] = {};

    const int srow = wave * 16 + (lane >> 2);
    const int scol = (lane & 3) * 8;
    const int lrow = lane & 15;
    const int lk   = (lane >> 4) * 8;

    const int npair = (MODE == 2) ? 3 : 1;
    for (int p = 0; p < npair; ++p) {
        const _Float16* Ap = (p == 0) ? A0 : ((p == 1) ? A1 : A2);
        const _Float16* Bp = (p == 0) ? B0 : ((p == 1) ? B1 : B2);
        const _Float16* Ab = Ap + (size_t)bm * 128 * Kp;
        const _Float16* Bb = Bp + (size_t)bn * 128 * Kp;
        for (int kt = 0; kt < Kp; kt += 32) {
            if (p | kt) __syncthreads();
            #pragma unroll
            for (int s = 0; s < 2; ++s) {
                const _Float16* ga = Ab + (size_t)(s * 64 + srow) * Kp + (kt + scol);
                const _Float16* gb = Bb + (size_t)(s * 64 + srow) * Kp + (kt + scol);
                __builtin_amdgcn_global_load_lds(
                    (const __attribute__((address_space(1))) void*)ga,
                    (__attribute__((address_space(3))) void*)(As + s * 2048 + wave * 512),
                    16, 0, 0);
                __builtin_amdgcn_global_load_lds(
                    (const __attribute__((address_space(1))) void*)gb,
                    (__attribute__((address_space(3))) void*)(Bs + s * 2048 + wave * 512),
                    16, 0, 0);
            }
            __syncthreads();
            f16x8 af[4], bf[4];
            #pragma unroll
            for (int m = 0; m < 4; ++m)
                af[m] = *(const f16x8*)(As + (wr * 64 + m * 16 + lrow) * 32 + lk);
            #pragma unroll
            for (int n = 0; n < 4; ++n)
                bf[n] = *(const f16x8*)(Bs + (wc * 64 + n * 16 + lrow) * 32 + lk);
            #pragma unroll
            for (int m = 0; m < 4; ++m)
                #pragma unroll
                for (int n = 0; n < 4; ++n)
                    acc[m][n] = __builtin_amdgcn_mfma_f32_16x16x32_f16(af[m], bf[n], acc[m][n], 0, 0, 0);
        }
        if (MODE == 2 && p == 1) {
            #pragma unroll
            for (int m = 0; m < 4; ++m)
                #pragma unroll
                for (int n = 0; n < 4; ++n)
                    acc[m][n] *= (1.0f / 2048.0f);
        }
    }

    // epilogue; C/D layout: col = lane&15, row = (lane>>4)*4 + reg
    const int r0 = bm * 128 + wr * 64 + (lane >> 4) * 4;
    const int c0 = bn * 128 + wc * 64 + (lane & 15);
    #pragma unroll
    for (int m = 0; m < 4; ++m) {
        #pragma unroll
        for (int n = 0; n < 4; ++n) {
            #pragma unroll
            for (int rr = 0; rr < 4; ++rr) {
                const int row = r0 + m * 16 + rr;
                const int col = c0 + n * 16;
                const size_t idx = (size_t)row * N + col;
                if (MODE == 1) {
                    float g = (float)GP[idx];
                    GP[idx] = (_Float16)(g * acc[m][n][rr]);
                } else {
                    Cf[idx] = acc[m][n][rr];
                }
            }
        }
    }
}

// ---------------- exact K-th largest |gate| per token + fused mask write ----------------

__global__ __launch_bounds__(256) void topk_mask(const float* __restrict__ gate,
                                                 _Float16* __restrict__ gm) {
    __shared__ unsigned keys[IDIM];
    __shared__ unsigned hist[256];
    __shared__ unsigned sA[256], sB[256];
    __shared__ unsigned selBin, selAbove;

    const int tid = threadIdx.x;
    const int t = blockIdx.x;
    const float* row = gate + (size_t)t * IDIM;

    for (int j = tid; j < IDIM; j += 256)
        keys[j] = __float_as_uint(fabsf(row[j]));
    __syncthreads();

    unsigned prefix = 0;
    int Krem = KKEEP;
    for (int pass = 0; pass < 4; ++pass) {
        const int shift = 24 - 8 * pass;
        hist[tid] = 0;
        __syncthreads();
        for (int j = tid; j < IDIM; j += 256) {
            unsigned k = keys[j];
            bool ok = (pass == 0) || (((k ^ prefix) >> (shift + 8)) == 0u);
            if (ok) atomicAdd(&hist[(k >> shift) & 255u], 1u);
        }
        __syncthreads();
        sA[tid] = hist[tid];
        __syncthreads();
        unsigned* src = sA; unsigned* dst = sB;
        for (int off = 1; off < 256; off <<= 1) {
            unsigned v = src[tid] + ((tid + off < 256) ? src[tid + off] : 0u);
            dst[tid] = v;
            __syncthreads();
            unsigned* tmp = src; src = dst; dst = tmp;
        }
        unsigned S  = src[tid];
        unsigned Sn = (tid < 255) ? src[tid + 1] : 0u;
        if ((int)S >= Krem && (int)Sn < Krem) { selBin = (unsigned)tid; selAbove = Sn; }
        __syncthreads();
        prefix |= (selBin << shift);
        Krem -= (int)selAbove;
        __syncthreads();
    }
    const float kthv = __uint_as_float(prefix);
    _Float16* g16 = gm + (size_t)t * IDIM;
    for (int j = tid; j < IDIM; j += 256) {
        float g = row[j];
        g16[j] = (fabsf(g) >= kthv) ? (_Float16)g : (_Float16)0.0f;
    }
}

// ---------------- host ----------------

extern "C" void kernel_launch(void* const* d_in, const int* in_sizes, int n_in,
                              void* d_out, int out_size, void* d_ws, size_t ws_size,
                              hipStream_t stream) {
    const float* x  = (const float*)d_in[0];   // [T,H]
    const float* Wg = (const float*)d_in[1];   // [I,H]
    const float* Wu = (const float*)d_in[2];   // [I,H]
    const float* Wd = (const float*)d_in[3];   // [H,I]

    const size_t NE   = (size_t)T_TOK * HDIM;  // == I*H == H*I element count
    const size_t szH2 = NE * 2;                // 33.55 MB (any f16 buffer)
    const size_t szGM = (size_t)T_TOK * IDIM * 2;  // 134.2 MB

    char* ws = (char*)d_ws;
    _Float16* xh    = (_Float16*)(ws + 0);
    _Float16* Wb    = (_Float16*)(ws + szH2);          // Wgh, later Wu16
    _Float16* Wc    = (_Float16*)(ws + 2 * szH2);      // Wgl2, later Wd16
    _Float16* gmask = (_Float16*)(ws + 3 * szH2);      // masked gate f16 -> P (in place)
    char* tail = ws + 3 * szH2 + szGM;
    const size_t base = 3 * szH2 + szGM;               // 234.9 MB
    const size_t avail = ws_size > base ? ws_size - base : 0;

    // xl2 lives in d_out scratch; gate f32 chunk in ws tail if it fits, else d_out
    _Float16* xl2 = (_Float16*)d_out;
    int Tc; float* gate;
    if      (avail >= (size_t)T_TOK * IDIM * 4) { Tc = T_TOK; gate = (float*)tail; }
    else if (avail >= (size_t)4096  * IDIM * 4) { Tc = 4096;  gate = (float*)tail; }
    else if (avail >= (size_t)2048  * IDIM * 4) { Tc = 2048;  gate = (float*)tail; }
    else if (avail >= (size_t)1024  * IDIM * 4) { Tc = 1024;  gate = (float*)tail; }
    else { Tc = 1024; gate = (float*)((char*)d_out + szH2); }

    const long n4 = (long)(NE / 4);
    cast_split<<<1024, 256, 0, stream>>>((const float4*)x,  (ushort4*)xh, (ushort4*)xl2, n4);
    cast_split<<<1024, 256, 0, stream>>>((const float4*)Wg, (ushort4*)Wb, (ushort4*)Wc,  n4);

    // gate phase (chunked): fused 3-pass split-f16 GEMM -> f32 gate, then top-k mask -> gmask f16
    for (int c0 = 0; c0 < T_TOK; c0 += Tc) {
        const _Float16* xh_c  = xh  + (size_t)c0 * HDIM;
        const _Float16* xl2_c = xl2 + (size_t)c0 * HDIM;
        dim3 g(Tc / 128, IDIM / 128);
        gemm_k<2><<<g, 256, 0, stream>>>(xl2_c, Wb, xh_c, Wc, xh_c, Wb,
                                         IDIM, HDIM, gate, nullptr);
        topk_mask<<<Tc, 256, 0, stream>>>(gate, gmask + (size_t)c0 * IDIM);
    }

    // re-cast weight slots for UP / DOWN
    cast_f16<<<1024, 256, 0, stream>>>((const float4*)Wu, (ushort4*)Wb, n4);
    cast_f16<<<1024, 256, 0, stream>>>((const float4*)Wd, (ushort4*)Wc, n4);

    // UP: full-size, in-place P = gmask * (xh @ Wu^T)
    gemm_k<1><<<dim3(T_TOK / 128, IDIM / 128), 256, 0, stream>>>(
        xh, Wb, nullptr, nullptr, nullptr, nullptr, IDIM, HDIM, nullptr, gmask);

    // DOWN: full-size, out = P @ Wd^T (overwrites all of d_out; scratch use of d_out done)
    gemm_k<0><<<dim3(T_TOK / 128, HDIM / 128), 256, 0, stream>>>(
        (const _Float16*)gmask, Wc, nullptr, nullptr, nullptr, nullptr,
        HDIM, IDIM, (float*)d_out, nullptr);
}

// Round 3
// 2025.566 us; speedup vs baseline: 1.6934x; 1.2286x over previous
//
#include <hip/hip_runtime.h>

#define T_TOK 8192   // B*S tokens
#define HDIM  2048
#define IDIM  8192
#define KKEEP 4096

typedef _Float16 f16x8 __attribute__((ext_vector_type(8)));
typedef float    f32x4 __attribute__((ext_vector_type(4)));

#define AS1 __attribute__((address_space(1)))
#define AS3 __attribute__((address_space(3)))

// ---------------- cast kernels ----------------

__global__ void cast_split(const float4* __restrict__ in, ushort4* __restrict__ hi,
                           ushort4* __restrict__ lo2, long n4) {
    long stride = (long)gridDim.x * blockDim.x;
    for (long i = (long)blockIdx.x * blockDim.x + threadIdx.x; i < n4; i += stride) {
        float4 v = in[i];
        float vv[4] = {v.x, v.y, v.z, v.w};
        union { _Float16 f[4]; ushort4 u; } H, L;
        #pragma unroll
        for (int j = 0; j < 4; ++j) {
            _Float16 h = (_Float16)vv[j];
            H.f[j] = h;
            L.f[j] = (_Float16)((vv[j] - (float)h) * 2048.0f);
        }
        hi[i] = H.u;
        lo2[i] = L.u;
    }
}

__global__ void cast_f16(const float4* __restrict__ in, ushort4* __restrict__ o, long n4) {
    long stride = (long)gridDim.x * blockDim.x;
    for (long i = (long)blockIdx.x * blockDim.x + threadIdx.x; i < n4; i += stride) {
        float4 v = in[i];
        float vv[4] = {v.x, v.y, v.z, v.w};
        union { _Float16 f[4]; ushort4 u; } H;
        #pragma unroll
        for (int j = 0; j < 4; ++j) H.f[j] = (_Float16)vv[j];
        o[i] = H.u;
    }
}

// ---------------- 256x256 8-phase GEMM (NT layout), T2+T3+T4+T5 ----------------
// MODE 0: DOWN — Cf = A0@B0^T (f32)
// MODE 1: UP   — in-place GP[idx] = (f16)((float)GP[idx] * acc)
// MODE 2: GATE — acc = A0@B0^T + A1@B1^T; acc *= 2^-11; acc += A2@B2^T; Cf f32

#define READA(mh_, buf_) do { \
    const char* ba_ = Lc + (buf_)*65536 + (mh_)*16384; \
    _Pragma("unroll") \
    for (int f_ = 0; f_ < 4; ++f_) { \
      _Pragma("unroll") \
      for (int k_ = 0; k_ < 2; ++k_) \
        afr[f_][k_] = *(const f16x8*)(ba_ + physA[f_][k_]); \
    } \
  } while (0)

#define READB(nh_, buf_) do { \
    const char* bb_ = Lc + (buf_)*65536 + 32768 + (nh_)*16384; \
    _Pragma("unroll") \
    for (int n_ = 0; n_ < 2; ++n_) { \
      _Pragma("unroll") \
      for (int k_ = 0; k_ < 2; ++k_) \
        bfr[n_][k_] = *(const f16x8*)(bb_ + physB[n_][k_]); \
    } \
  } while (0)

#define QUAD(mh_, nh_) do { \
    _Pragma("unroll") \
    for (int f_ = 0; f_ < 4; ++f_) { \
      _Pragma("unroll") \
      for (int n_ = 0; n_ < 2; ++n_) { \
        _Pragma("unroll") \
        for (int k_ = 0; k_ < 2; ++k_) \
          acc[(mh_)*4+f_][(nh_)*2+n_] = __builtin_amdgcn_mfma_f32_16x16x32_f16( \
              afr[f_][k_], bfr[n_][k_], acc[(mh_)*4+f_][(nh_)*2+n_], 0, 0, 0); \
      } \
    } \
  } while (0)

// stage one half-tile: mat_ 0=A 1=B, h_ half, buf_ target K-tile buffer
#define STAGE(ok_, pA_, pB_, kt_, mat_, h_, buf_) do { \
    if (ok_) { \
      const _Float16* mb_ = (mat_) == 0 ? (pA_) : (pB_); \
      const int rb_ = ((mat_) == 0 ? bm : bn) * 256 + (h_)*128; \
      char* ld_ = ldsw + (buf_)*65536 + (mat_)*32768 + (h_)*16384; \
      __builtin_amdgcn_global_load_lds((const AS1 void*)(mb_ + (size_t)(rb_ + srow0)*Kp + (kt_) + scol0), \
                                       (AS3 void*)ld_, 16, 0, 0); \
      __builtin_amdgcn_global_load_lds((const AS1 void*)(mb_ + (size_t)(rb_ + srow1)*Kp + (kt_) + scol1), \
                                       (AS3 void*)(ld_ + 8192), 16, 0, 0); \
    } \
  } while (0)

#define MIDSYNC do { \
    asm volatile("s_barrier" ::: "memory"); \
    asm volatile("s_waitcnt lgkmcnt(0)" ::: "memory"); \
    __builtin_amdgcn_sched_barrier(0); \
    __builtin_amdgcn_s_setprio(1); \
  } while (0)

#define ENDSYNC do { \
    __builtin_amdgcn_s_setprio(0); \
    asm volatile("s_barrier" ::: "memory"); \
  } while (0)

template <int MODE>
__global__ __launch_bounds__(512, 2) void gemm8(
    const _Float16* __restrict__ A0, const _Float16* __restrict__ B0,
    const _Float16* __restrict__ A1, const _Float16* __restrict__ B1,
    const _Float16* __restrict__ A2, const _Float16* __restrict__ B2,
    int N, int Kp, float* __restrict__ Cf, _Float16* __restrict__ GP)
{
    __shared__ __align__(128) char Lc[131072];   // 2 bufs x (A 32K + B 32K)
    const int tid  = threadIdx.x;
    const int lane = tid & 63;
    const int wave = tid >> 6;
    const int wr = wave >> 2, wc = wave & 3;     // 2 x 4 waves, each 128x64 out

    // XCD-bijective swizzle of flattened block id
    const int gx = gridDim.x, gy = gridDim.y;
    const int nwg = gx * gy;
    const int orig = blockIdx.y * gx + blockIdx.x;
    const int q = nwg >> 3, r = nwg & 7, xcd = orig & 7, lid = orig >> 3;
    const int wg = (xcd < r ? xcd * (q + 1) : r * (q + 1) + (xcd - r) * q) + lid;
    const int bm = wg / gy, bn = wg % gy;

    // staging map: linear LDS dest (wave-uniform base + lane*16) <- inverse-swizzled global src
    const int p0 = tid * 16, p1 = p0 + 8192;                 // physical byte in half-tile
    const int l0 = p0 ^ (((p0 >> 9) & 1) << 5);
    const int l1 = p1 ^ (((p1 >> 9) & 1) << 5);
    const int srow0 = l0 >> 7, scol0 = (l0 & 127) >> 1;      // row in half, elem col
    const int srow1 = l1 >> 7, scol1 = (l1 & 127) >> 1;
    char* ldsw = Lc + wave * 1024;

    // swizzled ds_read byte offsets (within half-tile)
    int physA[4][2], physB[2][2];
    #pragma unroll
    for (int f = 0; f < 4; ++f)
      #pragma unroll
      for (int k = 0; k < 2; ++k) {
        int ell = (wr * 64 + f * 16 + (lane & 15)) * 128 + (k * 32 + (lane >> 4) * 8) * 2;
        physA[f][k] = ell ^ (((ell >> 9) & 1) << 5);
      }
    #pragma unroll
    for (int n = 0; n < 2; ++n)
      #pragma unroll
      for (int k = 0; k < 2; ++k) {
        int ell = (wc * 32 + n * 16 + (lane & 15)) * 128 + (k * 32 + (lane >> 4) * 8) * 2;
        physB[n][k] = ell ^ (((ell >> 9) & 1) << 5);
      }

    const int tpp = Kp >> 6;                      // K-tiles per pass (>= 32 here)
    const int NT  = (MODE == 2 ? 3 : 1) * tpp;

    f32x4 acc[8][4] = {};
    f16x8 afr[4][2], bfr[2][2];

    // prologue: stage t0 {Bh0, Ah1, Ah0, Bh1} -> buf0, t1 {Bh0, Ah1} -> buf1
    STAGE(true, A0, B0, 0,  1, 0, 0);
    STAGE(true, A0, B0, 0,  0, 1, 0);
    STAGE(true, A0, B0, 0,  0, 0, 0);
    STAGE(true, A0, B0, 0,  1, 1, 0);
    STAGE(true, A0, B0, 64, 1, 0, 1);
    STAGE(true, A0, B0, 64, 0, 1, 1);
    asm volatile("s_waitcnt vmcnt(4)" ::: "memory");   // t0 fully landed
    asm volatile("s_barrier" ::: "memory");

    for (int t = 0; t < NT; ++t) {
        const int buf = t & 1;
        if (MODE == 2 && t == 2 * tpp) {
            #pragma unroll
            for (int m = 0; m < 8; ++m)
                #pragma unroll
                for (int n = 0; n < 4; ++n)
                    acc[m][n] *= (1.0f / 2048.0f);
        }
        // resolve stage tiles t+1, t+2 (uniform)
        const int ts1 = t + 1, ts2 = t + 2;
        const bool ok1 = ts1 < NT, ok2 = ts2 < NT;
        const _Float16 *pA1 = A0, *pB1 = B0, *pA2 = A0, *pB2 = B0;
        int kt1 = 0, kt2 = 0;
        if (MODE == 2) {
            if (ok1) { int ps = ts1 / tpp; kt1 = (ts1 - ps * tpp) << 6;
                       pA1 = ps == 0 ? A0 : (ps == 1 ? A1 : A2);
                       pB1 = ps == 0 ? B0 : (ps == 1 ? B1 : B2); }
            if (ok2) { int ps = ts2 / tpp; kt2 = (ts2 - ps * tpp) << 6;
                       pA2 = ps == 0 ? A0 : (ps == 1 ? A1 : A2);
                       pB2 = ps == 0 ? B0 : (ps == 1 ? B1 : B2); }
        } else { kt1 = ts1 << 6; kt2 = ts2 << 6; }

        // ph0: quad (mh0,nh0)
        READA(0, buf); READB(0, buf);
        STAGE(ok1, pA1, pB1, kt1, 0, 0, buf ^ 1);          // (t+1) Ah0
        MIDSYNC; QUAD(0, 0); ENDSYNC;
        // ph1: quad (mh1,nh0)
        READA(1, buf);
        STAGE(ok1, pA1, pB1, kt1, 1, 1, buf ^ 1);          // (t+1) Bh1
        asm volatile("s_waitcnt vmcnt(8)" ::: "memory");   // covers (t) Bh1 for ph2
        MIDSYNC; QUAD(1, 0); ENDSYNC;
        // ph2: quad (mh1,nh1)
        READB(1, buf);
        STAGE(ok2, pA2, pB2, kt2, 1, 0, buf);              // (t+2) Bh0
        MIDSYNC; QUAD(1, 1); ENDSYNC;
        // ph3: quad (mh0,nh1)
        READA(0, buf);
        STAGE(ok2, pA2, pB2, kt2, 0, 1, buf);              // (t+2) Ah1
        asm volatile("s_waitcnt vmcnt(6)" ::: "memory");   // covers (t+1) Ah0/Bh0 for next ph0
        MIDSYNC; QUAD(0, 1); ENDSYNC;
    }

    // epilogue; C/D layout: col = lane&15, row = (lane>>4)*4 + reg
    const int r0 = bm * 256 + wr * 64 + (lane >> 4) * 4;
    const int c0 = bn * 256 + wc * 32 + (lane & 15);
    #pragma unroll
    for (int mf = 0; mf < 8; ++mf) {
        const int row = r0 + (mf >> 2) * 128 + (mf & 3) * 16;
        #pragma unroll
        for (int nf = 0; nf < 4; ++nf) {
            const int col = c0 + (nf >> 1) * 128 + (nf & 1) * 16;
            #pragma unroll
            for (int rr = 0; rr < 4; ++rr) {
                const size_t idx = (size_t)(row + rr) * N + col;
                if (MODE == 1) {
                    float g = (float)GP[idx];
                    GP[idx] = (_Float16)(g * acc[mf][nf][rr]);
                } else {
                    Cf[idx] = acc[mf][nf][rr];
                }
            }
        }
    }
}

// ---------------- exact K-th largest |gate| per token + fused mask write ----------------

__global__ __launch_bounds__(256) void topk_mask(const float* __restrict__ gate,
                                                 _Float16* __restrict__ gm) {
    __shared__ unsigned keys[IDIM];
    __shared__ unsigned hist[256];
    __shared__ unsigned sA[256], sB[256];
    __shared__ unsigned selBin, selAbove;

    const int tid = threadIdx.x;
    const int t = blockIdx.x;
    const float* row = gate + (size_t)t * IDIM;

    for (int j = tid; j < IDIM; j += 256)
        keys[j] = __float_as_uint(fabsf(row[j]));
    __syncthreads();

    unsigned prefix = 0;
    int Krem = KKEEP;
    for (int pass = 0; pass < 4; ++pass) {
        const int shift = 24 - 8 * pass;
        hist[tid] = 0;
        __syncthreads();
        for (int j = tid; j < IDIM; j += 256) {
            unsigned k = keys[j];
            bool ok = (pass == 0) || (((k ^ prefix) >> (shift + 8)) == 0u);
            if (ok) atomicAdd(&hist[(k >> shift) & 255u], 1u);
        }
        __syncthreads();
        sA[tid] = hist[tid];
        __syncthreads();
        unsigned* src = sA; unsigned* dst = sB;
        for (int off = 1; off < 256; off <<= 1) {
            unsigned v = src[tid] + ((tid + off < 256) ? src[tid + off] : 0u);
            dst[tid] = v;
            __syncthreads();
            unsigned* tmp = src; src = dst; dst = tmp;
        }
        unsigned S  = src[tid];
        unsigned Sn = (tid < 255) ? src[tid + 1] : 0u;
        if ((int)S >= Krem && (int)Sn < Krem) { selBin = (unsigned)tid; selAbove = Sn; }
        __syncthreads();
        prefix |= (selBin << shift);
        Krem -= (int)selAbove;
        __syncthreads();
    }
    const float kthv = __uint_as_float(prefix);
    _Float16* g16 = gm + (size_t)t * IDIM;
    for (int j = tid; j < IDIM; j += 256) {
        float g = row[j];
        g16[j] = (fabsf(g) >= kthv) ? (_Float16)g : (_Float16)0.0f;
    }
}

// ---------------- host ----------------

extern "C" void kernel_launch(void* const* d_in, const int* in_sizes, int n_in,
                              void* d_out, int out_size, void* d_ws, size_t ws_size,
                              hipStream_t stream) {
    const float* x  = (const float*)d_in[0];   // [T,H]
    const float* Wg = (const float*)d_in[1];   // [I,H]
    const float* Wu = (const float*)d_in[2];   // [I,H]
    const float* Wd = (const float*)d_in[3];   // [H,I]

    const size_t NE   = (size_t)T_TOK * HDIM;
    const size_t szH2 = NE * 2;                          // 33.55 MB

    char* ws = (char*)d_ws;
    _Float16* xh    = (_Float16*)ws;
    _Float16* Wb    = (_Float16*)(ws + szH2);            // Wgh, later Wu16
    _Float16* Wc    = (_Float16*)(ws + 2 * szH2);        // Wgl2, later Wd16
    _Float16* gmask = (_Float16*)(ws + 3 * szH2);        // masked gate f16 -> P (in place)
    // xl2 parks in gmask's last quarter: consumed by chunk-3 GEMM before chunk-3
    // topk overwrites that region (stream-ordered; earlier chunks write lower rows).
    _Float16* xl2   = gmask + (size_t)6144 * IDIM;
    // gate f32 chunk (2048 x 8192 x 4B = 67.1 MB) lives in d_out; DOWN overwrites at the end.
    float* gate = (float*)d_out;

    const long n4 = (long)(NE / 4);
    cast_split<<<1024, 256, 0, stream>>>((const float4*)x,  (ushort4*)xh, (ushort4*)xl2, n4);
    cast_split<<<1024, 256, 0, stream>>>((const float4*)Wg, (ushort4*)Wb, (ushort4*)Wc,  n4);

    // gate phase: fused 3-pass split-f16 GEMM (f32 acc) -> exact top-k mask -> gmask f16
    for (int c0 = 0; c0 < T_TOK; c0 += 2048) {
        const _Float16* xh_c  = xh  + (size_t)c0 * HDIM;
        const _Float16* xl2_c = xl2 + (size_t)c0 * HDIM;
        gemm8<2><<<dim3(2048 / 256, IDIM / 256), 512, 0, stream>>>(
            xl2_c, Wb, xh_c, Wc, xh_c, Wb, IDIM, HDIM, gate, nullptr);
        topk_mask<<<2048, 256, 0, stream>>>(gate, gmask + (size_t)c0 * IDIM);
    }

    // re-cast weight slots for UP / DOWN
    cast_f16<<<1024, 256, 0, stream>>>((const float4*)Wu, (ushort4*)Wb, n4);
    cast_f16<<<1024, 256, 0, stream>>>((const float4*)Wd, (ushort4*)Wc, n4);

    // UP: in-place P = gmask * (xh @ Wu^T)
    gemm8<1><<<dim3(T_TOK / 256, IDIM / 256), 512, 0, stream>>>(
        xh, Wb, nullptr, nullptr, nullptr, nullptr, IDIM, HDIM, nullptr, gmask);

    // DOWN: out = P @ Wd^T
    gemm8<0><<<dim3(T_TOK / 256, HDIM / 256), 512, 0, stream>>>(
        (const _Float16*)gmask, Wc, nullptr, nullptr, nullptr, nullptr,
        HDIM, IDIM, (float*)d_out, nullptr);
}

// Round 4
// 1932.350 us; speedup vs baseline: 1.7751x; 1.0482x over previous
//
#include <hip/hip_runtime.h>

#define T_TOK 8192   // B*S tokens
#define HDIM  2048
#define IDIM  8192
#define KKEEP 4096

typedef _Float16 f16x8 __attribute__((ext_vector_type(8)));
typedef float    f32x4 __attribute__((ext_vector_type(4)));

#define AS1 __attribute__((address_space(1)))
#define AS3 __attribute__((address_space(3)))

// LDS physical<->logical swizzle within a 16KB half-tile (128 rows x 128B):
// XOR byte bits 4-6 with row bits 0-2  ->  each quarter-wave's 16 rows spread
// across all 8 16B bank-groups (2-way = free).  Involution.
__device__ __forceinline__ int swz(int b) { return b ^ (((b >> 7) & 7) << 4); }

// ---------------- cast kernels ----------------

__global__ void cast_split(const float4* __restrict__ in, ushort4* __restrict__ hi,
                           ushort4* __restrict__ lo2, long n4) {
    long stride = (long)gridDim.x * blockDim.x;
    for (long i = (long)blockIdx.x * blockDim.x + threadIdx.x; i < n4; i += stride) {
        float4 v = in[i];
        float vv[4] = {v.x, v.y, v.z, v.w};
        union { _Float16 f[4]; ushort4 u; } H, L;
        #pragma unroll
        for (int j = 0; j < 4; ++j) {
            _Float16 h = (_Float16)vv[j];
            H.f[j] = h;
            L.f[j] = (_Float16)((vv[j] - (float)h) * 2048.0f);
        }
        hi[i] = H.u;
        lo2[i] = L.u;
    }
}

__global__ void cast_f16(const float4* __restrict__ in, ushort4* __restrict__ o, long n4) {
    long stride = (long)gridDim.x * blockDim.x;
    for (long i = (long)blockIdx.x * blockDim.x + threadIdx.x; i < n4; i += stride) {
        float4 v = in[i];
        float vv[4] = {v.x, v.y, v.z, v.w};
        union { _Float16 f[4]; ushort4 u; } H;
        #pragma unroll
        for (int j = 0; j < 4; ++j) H.f[j] = (_Float16)vv[j];
        o[i] = H.u;
    }
}

// ---------------- 256x256 8-phase GEMM (NT layout), T2+T3+T4+T5 ----------------
// MODE 0: DOWN — Cf = A0@B0^T (f32)
// MODE 1: UP   — in-place GP[idx] = (f16)((float)GP[idx] * acc)
// MODE 2: GATE — acc = A0@B0^T + A1@B1^T; acc *= 2^-11; acc += A2@B2^T; Cf f32

#define READA(mh_, buf_) do { \
    const char* ba_ = Lc + (buf_)*65536 + (mh_)*16384; \
    _Pragma("unroll") \
    for (int f_ = 0; f_ < 4; ++f_) { \
      _Pragma("unroll") \
      for (int k_ = 0; k_ < 2; ++k_) \
        afr[f_][k_] = *(const f16x8*)(ba_ + physA[f_][k_]); \
    } \
  } while (0)

#define READB(nh_, buf_) do { \
    const char* bb_ = Lc + (buf_)*65536 + 32768 + (nh_)*16384; \
    _Pragma("unroll") \
    for (int n_ = 0; n_ < 2; ++n_) { \
      _Pragma("unroll") \
      for (int k_ = 0; k_ < 2; ++k_) \
        bfr[n_][k_] = *(const f16x8*)(bb_ + physB[n_][k_]); \
    } \
  } while (0)

#define QUAD(mh_, nh_) do { \
    _Pragma("unroll") \
    for (int f_ = 0; f_ < 4; ++f_) { \
      _Pragma("unroll") \
      for (int n_ = 0; n_ < 2; ++n_) { \
        _Pragma("unroll") \
        for (int k_ = 0; k_ < 2; ++k_) \
          acc[(mh_)*4+f_][(nh_)*2+n_] = __builtin_amdgcn_mfma_f32_16x16x32_f16( \
              afr[f_][k_], bfr[n_][k_], acc[(mh_)*4+f_][(nh_)*2+n_], 0, 0, 0); \
      } \
    } \
  } while (0)

// stage one half-tile: mat_ 0=A 1=B, h_ half, buf_ target K-tile buffer
#define STAGE(ok_, pA_, pB_, kt_, mat_, h_, buf_) do { \
    if (ok_) { \
      const _Float16* mb_ = (mat_) == 0 ? (pA_) : (pB_); \
      const int rb_ = ((mat_) == 0 ? bm : bn) * 256 + (h_)*128; \
      char* ld_ = ldsw + (buf_)*65536 + (mat_)*32768 + (h_)*16384; \
      __builtin_amdgcn_global_load_lds((const AS1 void*)(mb_ + (size_t)(rb_ + srow0)*Kp + (kt_) + scol0), \
                                       (AS3 void*)ld_, 16, 0, 0); \
      __builtin_amdgcn_global_load_lds((const AS1 void*)(mb_ + (size_t)(rb_ + srow1)*Kp + (kt_) + scol1), \
                                       (AS3 void*)(ld_ + 8192), 16, 0, 0); \
    } \
  } while (0)

#define MIDSYNC do { \
    asm volatile("s_barrier" ::: "memory"); \
    asm volatile("s_waitcnt lgkmcnt(0)" ::: "memory"); \
    __builtin_amdgcn_sched_barrier(0); \
    __builtin_amdgcn_s_setprio(1); \
  } while (0)

#define ENDSYNC do { \
    __builtin_amdgcn_s_setprio(0); \
    asm volatile("s_barrier" ::: "memory"); \
  } while (0)

template <int MODE>
__global__ __launch_bounds__(512, 2) void gemm8(
    const _Float16* __restrict__ A0, const _Float16* __restrict__ B0,
    const _Float16* __restrict__ A1, const _Float16* __restrict__ B1,
    const _Float16* __restrict__ A2, const _Float16* __restrict__ B2,
    int N, int Kp, float* __restrict__ Cf, _Float16* __restrict__ GP)
{
    __shared__ __align__(128) char Lc[131072];   // 2 bufs x (A 32K + B 32K)
    const int tid  = threadIdx.x;
    const int lane = tid & 63;
    const int wave = tid >> 6;
    const int wr = wave >> 2, wc = wave & 3;     // 2 x 4 waves, each 128x64 out

    // XCD-bijective swizzle of flattened block id
    const int gx = gridDim.x, gy = gridDim.y;
    const int nwg = gx * gy;
    const int orig = blockIdx.y * gx + blockIdx.x;
    const int q = nwg >> 3, r = nwg & 7, xcd = orig & 7, lid = orig >> 3;
    const int wg = (xcd < r ? xcd * (q + 1) : r * (q + 1) + (xcd - r) * q) + lid;
    const int bm = wg / gy, bn = wg % gy;

    // staging map: linear LDS dest (wave-uniform base + lane*16) <- inverse-swizzled global src
    const int p0 = tid * 16, p1 = p0 + 8192;                 // physical byte in half-tile
    const int l0 = swz(p0);
    const int l1 = swz(p1);
    const int srow0 = l0 >> 7, scol0 = (l0 & 127) >> 1;      // row in half, elem col
    const int srow1 = l1 >> 7, scol1 = (l1 & 127) >> 1;
    char* ldsw = Lc + wave * 1024;

    // swizzled ds_read byte offsets (within half-tile)
    int physA[4][2], physB[2][2];
    #pragma unroll
    for (int f = 0; f < 4; ++f)
      #pragma unroll
      for (int k = 0; k < 2; ++k) {
        int ell = (wr * 64 + f * 16 + (lane & 15)) * 128 + (k * 32 + (lane >> 4) * 8) * 2;
        physA[f][k] = swz(ell);
      }
    #pragma unroll
    for (int n = 0; n < 2; ++n)
      #pragma unroll
      for (int k = 0; k < 2; ++k) {
        int ell = (wc * 32 + n * 16 + (lane & 15)) * 128 + (k * 32 + (lane >> 4) * 8) * 2;
        physB[n][k] = swz(ell);
      }

    const int tpp = Kp >> 6;                      // K-tiles per pass
    const int NT  = (MODE == 2 ? 3 : 1) * tpp;

    f32x4 acc[8][4] = {};
    f16x8 afr[4][2], bfr[2][2];

    // prologue: stage t0 {Bh0, Ah1, Ah0, Bh1} -> buf0, t1 {Bh0, Ah1} -> buf1
    STAGE(true, A0, B0, 0,  1, 0, 0);
    STAGE(true, A0, B0, 0,  0, 1, 0);
    STAGE(true, A0, B0, 0,  0, 0, 0);
    STAGE(true, A0, B0, 0,  1, 1, 0);
    STAGE(true, A0, B0, 64, 1, 0, 1);
    STAGE(true, A0, B0, 64, 0, 1, 1);
    asm volatile("s_waitcnt vmcnt(4)" ::: "memory");   // t0 fully landed
    asm volatile("s_barrier" ::: "memory");

    for (int t = 0; t < NT; ++t) {
        const int buf = t & 1;
        if (MODE == 2 && t == 2 * tpp) {
            #pragma unroll
            for (int m = 0; m < 8; ++m)
                #pragma unroll
                for (int n = 0; n < 4; ++n)
                    acc[m][n] *= (1.0f / 2048.0f);
        }
        // resolve stage tiles t+1, t+2 (uniform)
        const int ts1 = t + 1, ts2 = t + 2;
        const bool ok1 = ts1 < NT, ok2 = ts2 < NT;
        const _Float16 *pA1 = A0, *pB1 = B0, *pA2 = A0, *pB2 = B0;
        int kt1 = 0, kt2 = 0;
        if (MODE == 2) {
            if (ok1) { int ps = ts1 / tpp; kt1 = (ts1 - ps * tpp) << 6;
                       pA1 = ps == 0 ? A0 : (ps == 1 ? A1 : A2);
                       pB1 = ps == 0 ? B0 : (ps == 1 ? B1 : B2); }
            if (ok2) { int ps = ts2 / tpp; kt2 = (ts2 - ps * tpp) << 6;
                       pA2 = ps == 0 ? A0 : (ps == 1 ? A1 : A2);
                       pB2 = ps == 0 ? B0 : (ps == 1 ? B1 : B2); }
        } else { kt1 = ts1 << 6; kt2 = ts2 << 6; }

        // ph0: quad (mh0,nh0)
        READA(0, buf); READB(0, buf);
        STAGE(ok1, pA1, pB1, kt1, 0, 0, buf ^ 1);          // (t+1) Ah0
        MIDSYNC; QUAD(0, 0); ENDSYNC;
        // ph1: quad (mh1,nh0)
        READA(1, buf);
        STAGE(ok1, pA1, pB1, kt1, 1, 1, buf ^ 1);          // (t+1) Bh1
        asm volatile("s_waitcnt vmcnt(8)" ::: "memory");   // covers (t) Bh1 for ph2
        MIDSYNC; QUAD(1, 0); ENDSYNC;
        // ph2: quad (mh1,nh1)
        READB(1, buf);
        STAGE(ok2, pA2, pB2, kt2, 1, 0, buf);              // (t+2) Bh0
        MIDSYNC; QUAD(1, 1); ENDSYNC;
        // ph3: quad (mh0,nh1)
        READA(0, buf);
        STAGE(ok2, pA2, pB2, kt2, 0, 1, buf);              // (t+2) Ah1
        asm volatile("s_waitcnt vmcnt(6)" ::: "memory");   // covers (t+1) Ah0/Bh0 for next ph0
        MIDSYNC; QUAD(0, 1); ENDSYNC;
    }

    // epilogue; C/D layout: col = lane&15, row = (lane>>4)*4 + reg
    const int r0 = bm * 256 + wr * 64 + (lane >> 4) * 4;
    const int c0 = bn * 256 + wc * 32 + (lane & 15);
    #pragma unroll
    for (int mf = 0; mf < 8; ++mf) {
        const int row = r0 + (mf >> 2) * 128 + (mf & 3) * 16;
        #pragma unroll
        for (int nf = 0; nf < 4; ++nf) {
            const int col = c0 + (nf >> 1) * 128 + (nf & 1) * 16;
            #pragma unroll
            for (int rr = 0; rr < 4; ++rr) {
                const size_t idx = (size_t)(row + rr) * N + col;
                if (MODE == 1) {
                    float g = (float)GP[idx];
                    GP[idx] = (_Float16)(g * acc[mf][nf][rr]);
                } else {
                    Cf[idx] = acc[mf][nf][rr];
                }
            }
        }
    }
}

// ---------------- exact K-th largest |gate| per token + fused mask write ----------------

__global__ __launch_bounds__(256) void topk_mask(const float* __restrict__ gate,
                                                 _Float16* __restrict__ gm) {
    __shared__ unsigned keys[IDIM];
    __shared__ unsigned hist[256];
    __shared__ unsigned sA[256], sB[256];
    __shared__ unsigned selBin, selAbove;

    const int tid = threadIdx.x;
    const int t = blockIdx.x;
    const float* row = gate + (size_t)t * IDIM;

    for (int j = tid; j < IDIM; j += 256)
        keys[j] = __float_as_uint(fabsf(row[j]));
    __syncthreads();

    unsigned prefix = 0;
    int Krem = KKEEP;
    for (int pass = 0; pass < 4; ++pass) {
        const int shift = 24 - 8 * pass;
        hist[tid] = 0;
        __syncthreads();
        for (int j = tid; j < IDIM; j += 256) {
            unsigned k = keys[j];
            bool ok = (pass == 0) || (((k ^ prefix) >> (shift + 8)) == 0u);
            if (ok) atomicAdd(&hist[(k >> shift) & 255u], 1u);
        }
        __syncthreads();
        sA[tid] = hist[tid];
        __syncthreads();
        unsigned* src = sA; unsigned* dst = sB;
        for (int off = 1; off < 256; off <<= 1) {
            unsigned v = src[tid] + ((tid + off < 256) ? src[tid + off] : 0u);
            dst[tid] = v;
            __syncthreads();
            unsigned* tmp = src; src = dst; dst = tmp;
        }
        unsigned S  = src[tid];
        unsigned Sn = (tid < 255) ? src[tid + 1] : 0u;
        if ((int)S >= Krem && (int)Sn < Krem) { selBin = (unsigned)tid; selAbove = Sn; }
        __syncthreads();
        prefix |= (selBin << shift);
        Krem -= (int)selAbove;
        __syncthreads();
    }
    const float kthv = __uint_as_float(prefix);
    _Float16* g16 = gm + (size_t)t * IDIM;
    for (int j = tid; j < IDIM; j += 256) {
        float g = row[j];
        g16[j] = (fabsf(g) >= kthv) ? (_Float16)g : (_Float16)0.0f;
    }
}

// ---------------- host ----------------

extern "C" void kernel_launch(void* const* d_in, const int* in_sizes, int n_in,
                              void* d_out, int out_size, void* d_ws, size_t ws_size,
                              hipStream_t stream) {
    const float* x  = (const float*)d_in[0];   // [T,H]
    const float* Wg = (const float*)d_in[1];   // [I,H]
    const float* Wu = (const float*)d_in[2];   // [I,H]
    const float* Wd = (const float*)d_in[3];   // [H,I]

    const size_t NE   = (size_t)T_TOK * HDIM;
    const size_t szH2 = NE * 2;                          // 33.55 MB

    char* ws = (char*)d_ws;
    _Float16* xh    = (_Float16*)ws;
    _Float16* Wb    = (_Float16*)(ws + szH2);            // Wgh, later Wu16
    _Float16* Wc    = (_Float16*)(ws + 2 * szH2);        // Wgl2, later Wd16
    _Float16* gmask = (_Float16*)(ws + 3 * szH2);        // masked gate f16 -> P (in place)
    // xl2 parks in gmask's last quarter: consumed by chunk-3 GEMM before chunk-3
    // topk overwrites that region (stream-ordered; earlier chunks write lower rows).
    _Float16* xl2   = gmask + (size_t)6144 * IDIM;
    // gate f32 chunk (2048 x 8192 x 4B = 67.1 MB) lives in d_out; DOWN overwrites at the end.
    float* gate = (float*)d_out;

    const long n4 = (long)(NE / 4);
    cast_split<<<1024, 256, 0, stream>>>((const float4*)x,  (ushort4*)xh, (ushort4*)xl2, n4);
    cast_split<<<1024, 256, 0, stream>>>((const float4*)Wg, (ushort4*)Wb, (ushort4*)Wc,  n4);

    // gate phase: fused 3-pass split-f16 GEMM (f32 acc) -> exact top-k mask -> gmask f16
    for (int c0 = 0; c0 < T_TOK; c0 += 2048) {
        const _Float16* xh_c  = xh  + (size_t)c0 * HDIM;
        const _Float16* xl2_c = xl2 + (size_t)c0 * HDIM;
        gemm8<2><<<dim3(2048 / 256, IDIM / 256), 512, 0, stream>>>(
            xl2_c, Wb, xh_c, Wc, xh_c, Wb, IDIM, HDIM, gate, nullptr);
        topk_mask<<<2048, 256, 0, stream>>>(gate, gmask + (size_t)c0 * IDIM);
    }

    // re-cast weight slots for UP / DOWN
    cast_f16<<<1024, 256, 0, stream>>>((const float4*)Wu, (ushort4*)Wb, n4);
    cast_f16<<<1024, 256, 0, stream>>>((const float4*)Wd, (ushort4*)Wc, n4);

    // UP: in-place P = gmask * (xh @ Wu^T)
    gemm8<1><<<dim3(T_TOK / 256, IDIM / 256), 512, 0, stream>>>(
        xh, Wb, nullptr, nullptr, nullptr, nullptr, IDIM, HDIM, nullptr, gmask);

    // DOWN: out = P @ Wd^T
    gemm8<0><<<dim3(T_TOK / 256, HDIM / 256), 512, 0, stream>>>(
        (const _Float16*)gmask, Wc, nullptr, nullptr, nullptr, nullptr,
        HDIM, IDIM, (float*)d_out, nullptr);
}

// Round 5
// 1890.049 us; speedup vs baseline: 1.8149x; 1.0224x over previous
//
#include <hip/hip_runtime.h>

#define T_TOK 8192   // B*S tokens
#define HDIM  2048
#define IDIM  8192
#define KKEEP 4096

typedef _Float16 f16x8 __attribute__((ext_vector_type(8)));
typedef float    f32x4 __attribute__((ext_vector_type(4)));

#define AS1 __attribute__((address_space(1)))
#define AS3 __attribute__((address_space(3)))

// LDS swizzle within a 16KB half-tile (128 rows x 128B): byte ^= (row&7)<<4.
__device__ __forceinline__ int swz(int b) { return b ^ (((b >> 7) & 7) << 4); }

#define BARR asm volatile("s_barrier" ::: "memory")
#define SB0  __builtin_amdgcn_sched_barrier(0)

// ---------------- cast kernels ----------------

__global__ void cast_split(const float4* __restrict__ in, ushort4* __restrict__ hi,
                           ushort4* __restrict__ lo2, long n4) {
    long stride = (long)gridDim.x * blockDim.x;
    for (long i = (long)blockIdx.x * blockDim.x + threadIdx.x; i < n4; i += stride) {
        float4 v = in[i];
        float vv[4] = {v.x, v.y, v.z, v.w};
        union { _Float16 f[4]; ushort4 u; } H, L;
        #pragma unroll
        for (int j = 0; j < 4; ++j) {
            _Float16 h = (_Float16)vv[j];
            H.f[j] = h;
            L.f[j] = (_Float16)((vv[j] - (float)h) * 2048.0f);
        }
        hi[i] = H.u;
        lo2[i] = L.u;
    }
}

__global__ void cast_f16(const float4* __restrict__ in, ushort4* __restrict__ o, long n4) {
    long stride = (long)gridDim.x * blockDim.x;
    for (long i = (long)blockIdx.x * blockDim.x + threadIdx.x; i < n4; i += stride) {
        float4 v = in[i];
        float vv[4] = {v.x, v.y, v.z, v.w};
        union { _Float16 f[4]; ushort4 u; } H;
        #pragma unroll
        for (int j = 0; j < 4; ++j) H.f[j] = (_Float16)vv[j];
        o[i] = H.u;
    }
}

// ---------------- 256x256 8-phase GEMM, pipelined frag reads ----------------
// MODE 0: DOWN — Cf = A0@B0^T (f32)
// MODE 1: UP   — in-place GP[idx] = (f16)((float)GP[idx] * acc)
// MODE 2: GATE — acc = A0@B0^T + A1@B1^T; acc *= 2^-11; acc += A2@B2^T; Cf f32

#define RD_A(dst_, mh_, buf_) do { \
    const char* b_ = Lc + (buf_)*65536 + (mh_)*16384; \
    _Pragma("unroll") \
    for (int f_ = 0; f_ < 4; ++f_) { \
      (dst_)[f_][0] = *(const f16x8*)(b_ + aof0 + f_*2048); \
      (dst_)[f_][1] = *(const f16x8*)(b_ + aof1 + f_*2048); \
    } \
  } while (0)

#define RD_B(dst_, nh_, buf_) do { \
    const char* b_ = Lc + (buf_)*65536 + 32768 + (nh_)*16384; \
    _Pragma("unroll") \
    for (int n_ = 0; n_ < 2; ++n_) { \
      (dst_)[n_][0] = *(const f16x8*)(b_ + bof0 + n_*2048); \
      (dst_)[n_][1] = *(const f16x8*)(b_ + bof1 + n_*2048); \
    } \
  } while (0)

#define QUADM(af_, bf_, mh_, nh_) do { \
    _Pragma("unroll") \
    for (int f_ = 0; f_ < 4; ++f_) { \
      _Pragma("unroll") \
      for (int n_ = 0; n_ < 2; ++n_) { \
        _Pragma("unroll") \
        for (int k_ = 0; k_ < 2; ++k_) \
          acc[(mh_)*4+f_][(nh_)*2+n_] = __builtin_amdgcn_mfma_f32_16x16x32_f16( \
              (af_)[f_][k_], (bf_)[n_][k_], acc[(mh_)*4+f_][(nh_)*2+n_], 0, 0, 0); \
      } \
    } \
  } while (0)

// stage one half-tile: mat_ 0=A 1=B, h_ half, buf_ target buffer
#define STAGE(ok_, pA_, pB_, kt_, mat_, h_, buf_) do { \
    if (ok_) { \
      const _Float16* mb_ = (mat_) == 0 ? (pA_) : (pB_); \
      const int rb_ = ((mat_) == 0 ? bm : bn) * 256 + (h_)*128; \
      char* ld_ = ldsw + (buf_)*65536 + (mat_)*32768 + (h_)*16384; \
      __builtin_amdgcn_global_load_lds((const AS1 void*)(mb_ + (size_t)(rb_ + srow0)*Kp + (kt_) + scol0), \
                                       (AS3 void*)ld_, 16, 0, 0); \
      __builtin_amdgcn_global_load_lds((const AS1 void*)(mb_ + (size_t)(rb_ + srow1)*Kp + (kt_) + scol1), \
                                       (AS3 void*)(ld_ + 8192), 16, 0, 0); \
    } \
  } while (0)

template <int MODE>
__global__ __launch_bounds__(512, 2) void gemm8(
    const _Float16* __restrict__ A0, const _Float16* __restrict__ B0,
    const _Float16* __restrict__ A1, const _Float16* __restrict__ B1,
    const _Float16* __restrict__ A2, const _Float16* __restrict__ B2,
    int N, int Kp, float* __restrict__ Cf, _Float16* __restrict__ GP)
{
    __shared__ __align__(128) char Lc[131072];   // 2 bufs x (A 32K + B 32K)
    const int tid  = threadIdx.x;
    const int lane = tid & 63;
    const int wave = tid >> 6;
    const int wr = wave >> 2, wc = wave & 3;     // 2 x 4 waves

    // XCD-bijective swizzle of flattened block id
    const int gx = gridDim.x, gy = gridDim.y;
    const int nwg = gx * gy;
    const int orig = blockIdx.y * gx + blockIdx.x;
    const int q = nwg >> 3, r = nwg & 7, xcd = orig & 7, lid = orig >> 3;
    const int wg = (xcd < r ? xcd * (q + 1) : r * (q + 1) + (xcd - r) * q) + lid;
    const int bm = wg / gy, bn = wg % gy;

    // staging map: linear LDS dest <- inverse-swizzled global source
    const int p0 = tid * 16, p1 = p0 + 8192;
    const int l0 = swz(p0), l1 = swz(p1);
    const int srow0 = l0 >> 7, scol0 = (l0 & 127) >> 1;
    const int srow1 = l1 >> 7, scol1 = (l1 & 127) >> 1;
    char* ldsw = Lc + wave * 1024;

    // swizzled ds_read bases: row&7 == lane&7 for all frags -> constant XOR;
    // phys(f,k) = (LB ^ ax) + f*2048, bit6 toggled by k.
    const int l15 = lane & 15, lhi = lane >> 4, ax = (lane & 7) << 4;
    const int aof0 = (wr * 8192 + l15 * 128 + lhi * 16) ^ ax;
    const int aof1 = aof0 ^ 64;
    const int bof0 = (wc * 4096 + l15 * 128 + lhi * 16) ^ ax;
    const int bof1 = bof0 ^ 64;

    const int tpp = Kp >> 6;                      // K-tiles per pass
    const int NT  = (MODE == 2 ? 3 : 1) * tpp;

    f32x4 acc[8][4] = {};
    f16x8 a0f[4][2], a1f[4][2], b0f[2][2], b1f[2][2];

    // prologue: stage tile0 (4 half-tiles) + tile1's Ah1,Bh1
    STAGE(true, A0, B0, 0,  0, 0, 0);   // Ah0(0)
    STAGE(true, A0, B0, 0,  1, 0, 0);   // Bh0(0)
    STAGE(true, A0, B0, 0,  0, 1, 0);   // Ah1(0)
    STAGE(true, A0, B0, 0,  1, 1, 0);   // Bh1(0)
    STAGE(true, A0, B0, 64, 0, 1, 1);   // Ah1(1)
    STAGE(true, A0, B0, 64, 1, 1, 1);   // Bh1(1)
    asm volatile("s_waitcnt vmcnt(4)" ::: "memory");   // tile0 landed
    BARR;
    RD_A(a0f, 0, 0);
    RD_B(b0f, 0, 0);

    for (int t = 0; t < NT; ++t) {
        const int buf = t & 1;
        if (MODE == 2 && t == 2 * tpp) {
            #pragma unroll
            for (int m = 0; m < 8; ++m)
                #pragma unroll
                for (int n = 0; n < 4; ++n)
                    acc[m][n] *= (1.0f / 2048.0f);
        }
        const int ts1 = t + 1, ts2 = t + 2;
        const bool ok1 = ts1 < NT, ok2 = ts2 < NT;
        const _Float16 *pA1 = A0, *pB1 = B0, *pA2 = A0, *pB2 = B0;
        int kt1 = 0, kt2 = 0;
        if (MODE == 2) {
            if (ok1) { int ps = ts1 / tpp; kt1 = (ts1 - ps * tpp) << 6;
                       pA1 = ps == 0 ? A0 : (ps == 1 ? A1 : A2);
                       pB1 = ps == 0 ? B0 : (ps == 1 ? B1 : B2); }
            if (ok2) { int ps = ts2 / tpp; kt2 = (ts2 - ps * tpp) << 6;
                       pA2 = ps == 0 ? A0 : (ps == 1 ? A1 : A2);
                       pB2 = ps == 0 ? B0 : (ps == 1 ? B1 : B2); }
        } else { kt1 = ts1 << 6; kt2 = ts2 << 6; }

        // ph0: q00 (A0,B0); prefetch-read A1(t); stage Ah0(t+1)
        STAGE(ok1, pA1, pB1, kt1, 0, 0, buf ^ 1);
        BARR; SB0;
        RD_A(a1f, 1, buf);
        __builtin_amdgcn_s_setprio(1); QUADM(a0f, b0f, 0, 0); __builtin_amdgcn_s_setprio(0);
        SB0; BARR;

        // ph1: q10 (A1,B0); prefetch-read B1(t); stage Bh0(t+1)
        STAGE(ok1, pA1, pB1, kt1, 1, 0, buf ^ 1);
        BARR; SB0;
        RD_B(b1f, 1, buf);
        __builtin_amdgcn_s_setprio(1); QUADM(a1f, b0f, 1, 0); __builtin_amdgcn_s_setprio(0);
        SB0; BARR;

        // ph2: q11 (A1,B1); stage Ah1(t+2)
        STAGE(ok2, pA2, pB2, kt2, 0, 1, buf);
        BARR; SB0;
        __builtin_amdgcn_s_setprio(1); QUADM(a1f, b1f, 1, 1); __builtin_amdgcn_s_setprio(0);
        SB0; BARR;

        // ph3: q01 (A0,B1); stage Bh1(t+2); vmcnt publishes tile t+1; then
        // post-read A0(t+1),B0(t+1) to overlap next phases
        STAGE(ok2, pA2, pB2, kt2, 1, 1, buf);
        if (ok2) asm volatile("s_waitcnt vmcnt(4)" ::: "memory");
        else     asm volatile("s_waitcnt vmcnt(0)" ::: "memory");
        BARR; SB0;
        __builtin_amdgcn_s_setprio(1); QUADM(a0f, b1f, 0, 1); __builtin_amdgcn_s_setprio(0);
        SB0;
        if (ok1) { RD_A(a0f, 0, buf ^ 1); RD_B(b0f, 0, buf ^ 1); }
        BARR;
    }

    // epilogue; C/D layout: col = lane&15, row = (lane>>4)*4 + reg
    const int r0 = bm * 256 + wr * 64 + (lane >> 4) * 4;
    const int c0 = bn * 256 + wc * 32 + (lane & 15);
    #pragma unroll
    for (int mf = 0; mf < 8; ++mf) {
        const int row = r0 + (mf >> 2) * 128 + (mf & 3) * 16;
        #pragma unroll
        for (int nf = 0; nf < 4; ++nf) {
            const int col = c0 + (nf >> 1) * 128 + (nf & 1) * 16;
            #pragma unroll
            for (int rr = 0; rr < 4; ++rr) {
                const size_t idx = (size_t)(row + rr) * N + col;
                if (MODE == 1) {
                    float g = (float)GP[idx];
                    GP[idx] = (_Float16)(g * acc[mf][nf][rr]);
                } else {
                    Cf[idx] = acc[mf][nf][rr];
                }
            }
        }
    }
}

// ---------------- exact K-th largest |gate| per token + fused mask write ----------------

__global__ __launch_bounds__(256) void topk_mask(const float* __restrict__ gate,
                                                 _Float16* __restrict__ gm) {
    __shared__ unsigned keys[IDIM];
    __shared__ unsigned hist[256];
    __shared__ unsigned sA[256], sB[256];
    __shared__ unsigned selBin, selAbove;

    const int tid = threadIdx.x;
    const int t = blockIdx.x;
    const float* row = gate + (size_t)t * IDIM;

    for (int j = tid; j < IDIM; j += 256)
        keys[j] = __float_as_uint(fabsf(row[j]));
    __syncthreads();

    unsigned prefix = 0;
    int Krem = KKEEP;
    for (int pass = 0; pass < 4; ++pass) {
        const int shift = 24 - 8 * pass;
        hist[tid] = 0;
        __syncthreads();
        for (int j = tid; j < IDIM; j += 256) {
            unsigned k = keys[j];
            bool ok = (pass == 0) || (((k ^ prefix) >> (shift + 8)) == 0u);
            if (ok) atomicAdd(&hist[(k >> shift) & 255u], 1u);
        }
        __syncthreads();
        sA[tid] = hist[tid];
        __syncthreads();
        unsigned* src = sA; unsigned* dst = sB;
        for (int off = 1; off < 256; off <<= 1) {
            unsigned v = src[tid] + ((tid + off < 256) ? src[tid + off] : 0u);
            dst[tid] = v;
            __syncthreads();
            unsigned* tmp = src; src = dst; dst = tmp;
        }
        unsigned S  = src[tid];
        unsigned Sn = (tid < 255) ? src[tid + 1] : 0u;
        if ((int)S >= Krem && (int)Sn < Krem) { selBin = (unsigned)tid; selAbove = Sn; }
        __syncthreads();
        prefix |= (selBin << shift);
        Krem -= (int)selAbove;
        __syncthreads();
    }
    const float kthv = __uint_as_float(prefix);
    _Float16* g16 = gm + (size_t)t * IDIM;
    for (int j = tid; j < IDIM; j += 256) {
        float g = row[j];
        g16[j] = (fabsf(g) >= kthv) ? (_Float16)g : (_Float16)0.0f;
    }
}

// ---------------- host ----------------

extern "C" void kernel_launch(void* const* d_in, const int* in_sizes, int n_in,
                              void* d_out, int out_size, void* d_ws, size_t ws_size,
                              hipStream_t stream) {
    const float* x  = (const float*)d_in[0];   // [T,H]
    const float* Wg = (const float*)d_in[1];   // [I,H]
    const float* Wu = (const float*)d_in[2];   // [I,H]
    const float* Wd = (const float*)d_in[3];   // [H,I]

    const size_t NE   = (size_t)T_TOK * HDIM;
    const size_t szH2 = NE * 2;                          // 33.55 MB

    char* ws = (char*)d_ws;
    _Float16* xh    = (_Float16*)ws;
    _Float16* Wb    = (_Float16*)(ws + szH2);            // Wgh, later Wu16
    _Float16* Wc    = (_Float16*)(ws + 2 * szH2);        // Wgl2, later Wd16
    _Float16* gmask = (_Float16*)(ws + 3 * szH2);        // masked gate f16 -> P (in place)
    _Float16* xl2   = gmask + (size_t)6144 * IDIM;       // parked; consumed before overwritten
    float* gate = (float*)d_out;                         // 2048-token f32 gate chunk

    const long n4 = (long)(NE / 4);
    cast_split<<<1024, 256, 0, stream>>>((const float4*)x,  (ushort4*)xh, (ushort4*)xl2, n4);
    cast_split<<<1024, 256, 0, stream>>>((const float4*)Wg, (ushort4*)Wb, (ushort4*)Wc,  n4);

    // gate phase: fused 3-pass split-f16 GEMM (f32 acc) -> exact top-k mask -> gmask f16
    for (int c0 = 0; c0 < T_TOK; c0 += 2048) {
        const _Float16* xh_c  = xh  + (size_t)c0 * HDIM;
        const _Float16* xl2_c = xl2 + (size_t)c0 * HDIM;
        gemm8<2><<<dim3(2048 / 256, IDIM / 256), 512, 0, stream>>>(
            xl2_c, Wb, xh_c, Wc, xh_c, Wb, IDIM, HDIM, gate, nullptr);
        topk_mask<<<2048, 256, 0, stream>>>(gate, gmask + (size_t)c0 * IDIM);
    }

    // re-cast weight slots for UP / DOWN
    cast_f16<<<1024, 256, 0, stream>>>((const float4*)Wu, (ushort4*)Wb, n4);
    cast_f16<<<1024, 256, 0, stream>>>((const float4*)Wd, (ushort4*)Wc, n4);

    // UP: in-place P = gmask * (xh @ Wu^T)
    gemm8<1><<<dim3(T_TOK / 256, IDIM / 256), 512, 0, stream>>>(
        xh, Wb, nullptr, nullptr, nullptr, nullptr, IDIM, HDIM, nullptr, gmask);

    // DOWN: out = P @ Wd^T
    gemm8<0><<<dim3(T_TOK / 256, HDIM / 256), 512, 0, stream>>>(
        (const _Float16*)gmask, Wc, nullptr, nullptr, nullptr, nullptr,
        HDIM, IDIM, (float*)d_out, nullptr);
}

// Round 7
// 1839.585 us; speedup vs baseline: 1.8647x; 1.0274x over previous
//
#include <hip/hip_runtime.h>

#define T_TOK 8192   // B*S tokens
#define HDIM  2048
#define IDIM  8192
#define KKEEP 4096

typedef _Float16 f16x8 __attribute__((ext_vector_type(8)));
typedef float    f32x4 __attribute__((ext_vector_type(4)));

#define AS1 __attribute__((address_space(1)))
#define AS3 __attribute__((address_space(3)))

// LDS swizzle within a 16KB half-tile (128 rows x 128B): byte ^= (row&7)<<4.
__device__ __forceinline__ int swz(int b) { return b ^ (((b >> 7) & 7) << 4); }

#define BARR asm volatile("s_barrier" ::: "memory")

// ---------------- cast kernels ----------------

__global__ void cast_split(const float4* __restrict__ in, ushort4* __restrict__ hi,
                           ushort4* __restrict__ lo2, long n4) {
    long stride = (long)gridDim.x * blockDim.x;
    for (long i = (long)blockIdx.x * blockDim.x + threadIdx.x; i < n4; i += stride) {
        float4 v = in[i];
        float vv[4] = {v.x, v.y, v.z, v.w};
        union { _Float16 f[4]; ushort4 u; } H, L;
        #pragma unroll
        for (int j = 0; j < 4; ++j) {
            _Float16 h = (_Float16)vv[j];
            H.f[j] = h;
            L.f[j] = (_Float16)((vv[j] - (float)h) * 2048.0f);
        }
        hi[i] = H.u;
        lo2[i] = L.u;
    }
}

__global__ void cast_f16(const float4* __restrict__ in, ushort4* __restrict__ o, long n4) {
    long stride = (long)gridDim.x * blockDim.x;
    for (long i = (long)blockIdx.x * blockDim.x + threadIdx.x; i < n4; i += stride) {
        float4 v = in[i];
        float vv[4] = {v.x, v.y, v.z, v.w};
        union { _Float16 f[4]; ushort4 u; } H;
        #pragma unroll
        for (int j = 0; j < 4; ++j) H.f[j] = (_Float16)vv[j];
        o[i] = H.u;
    }
}

// ---------------- 256x256 GEMM, 1-barrier-per-phase, read-once frags ----------------
// MODE 0: DOWN — Cf = A0@B0^T (f32)
// MODE 1: UP   — in-place GP[idx] = (f16)((float)GP[idx] * acc)
// MODE 2: GATE — acc = A0@B0^T + A1@B1^T; acc *= 2^-11; acc += A2@B2^T; Cf f32

#define RD_A(dst_, mh_, buf_) do { \
    const char* b_ = Lc + (buf_)*65536 + (mh_)*16384; \
    _Pragma("unroll") \
    for (int f_ = 0; f_ < 4; ++f_) { \
      (dst_)[f_][0] = *(const f16x8*)(b_ + aof0 + f_*2048); \
      (dst_)[f_][1] = *(const f16x8*)(b_ + aof1 + f_*2048); \
    } \
  } while (0)

#define RD_B(dst_, nh_, buf_) do { \
    const char* b_ = Lc + (buf_)*65536 + 32768 + (nh_)*16384; \
    _Pragma("unroll") \
    for (int n_ = 0; n_ < 2; ++n_) { \
      (dst_)[n_][0] = *(const f16x8*)(b_ + bof0 + n_*2048); \
      (dst_)[n_][1] = *(const f16x8*)(b_ + bof1 + n_*2048); \
    } \
  } while (0)

#define QUADM(af_, bf_, mh_, nh_) do { \
    __builtin_amdgcn_s_setprio(1); \
    _Pragma("unroll") \
    for (int f_ = 0; f_ < 4; ++f_) { \
      _Pragma("unroll") \
      for (int n_ = 0; n_ < 2; ++n_) { \
        _Pragma("unroll") \
        for (int k_ = 0; k_ < 2; ++k_) \
          acc[(mh_)*4+f_][(nh_)*2+n_] = __builtin_amdgcn_mfma_f32_16x16x32_f16( \
              (af_)[f_][k_], (bf_)[n_][k_], acc[(mh_)*4+f_][(nh_)*2+n_], 0, 0, 0); \
      } \
    } \
    __builtin_amdgcn_s_setprio(0); \
  } while (0)

// stage one half-tile: mat_ 0=A 1=B, h_ half, buf_ target buffer
#define STAGE(ok_, pA_, pB_, kt_, mat_, h_, buf_) do { \
    if (ok_) { \
      const _Float16* mb_ = (mat_) == 0 ? (pA_) : (pB_); \
      const int rb_ = ((mat_) == 0 ? bm : bn) * 256 + (h_)*128; \
      char* ld_ = ldsw + (buf_)*65536 + (mat_)*32768 + (h_)*16384; \
      __builtin_amdgcn_global_load_lds((const AS1 void*)(mb_ + (size_t)(rb_ + srow0)*Kp + (kt_) + scol0), \
                                       (AS3 void*)ld_, 16, 0, 0); \
      __builtin_amdgcn_global_load_lds((const AS1 void*)(mb_ + (size_t)(rb_ + srow1)*Kp + (kt_) + scol1), \
                                       (AS3 void*)(ld_ + 8192), 16, 0, 0); \
    } \
  } while (0)

template <int MODE>
__global__ __launch_bounds__(512, 2) void gemm8(
    const _Float16* __restrict__ A0, const _Float16* __restrict__ B0,
    const _Float16* __restrict__ A1, const _Float16* __restrict__ B1,
    const _Float16* __restrict__ A2, const _Float16* __restrict__ B2,
    int N, int Kp, float* __restrict__ Cf, _Float16* __restrict__ GP)
{
    __shared__ __align__(128) char Lc[131072];   // 2 bufs x (A 32K + B 32K)
    const int tid  = threadIdx.x;
    const int lane = tid & 63;
    const int wave = tid >> 6;
    const int wr = wave >> 2, wc = wave & 3;     // 2 x 4 waves

    // XCD-bijective swizzle of flattened block id
    const int gx = gridDim.x, gy = gridDim.y;
    const int nwg = gx * gy;
    const int orig = blockIdx.y * gx + blockIdx.x;
    const int q = nwg >> 3, r = nwg & 7, xcd = orig & 7, lid = orig >> 3;
    const int wg = (xcd < r ? xcd * (q + 1) : r * (q + 1) + (xcd - r) * q) + lid;
    const int bm = wg / gy, bn = wg % gy;

    // staging map: linear LDS dest <- inverse-swizzled global source
    const int p0 = tid * 16, p1 = p0 + 8192;
    const int l0 = swz(p0), l1 = swz(p1);
    const int srow0 = l0 >> 7, scol0 = (l0 & 127) >> 1;
    const int srow1 = l1 >> 7, scol1 = (l1 & 127) >> 1;
    char* ldsw = Lc + wave * 1024;

    // swizzled ds_read bases: row&7 == lane&7 -> constant XOR; k toggles bit 6
    const int l15 = lane & 15, lhi = lane >> 4, ax = (lane & 7) << 4;
    const int aof0 = (wr * 8192 + l15 * 128 + lhi * 16) ^ ax;
    const int aof1 = aof0 ^ 64;
    const int bof0 = (wc * 4096 + l15 * 128 + lhi * 16) ^ ax;
    const int bof1 = bof0 ^ 64;

    const int tpp = Kp >> 6;                      // K-tiles per pass (>=32)
    const int NT  = (MODE == 2 ? 3 : 1) * tpp;

    f32x4 acc[8][4] = {};
    f16x8 a0f[4][2], a1f[4][2], bf[2][2];

    // prologue: tile0 all 4 halves -> buf0; tile1's Ah1,Bh1 -> buf1
    STAGE(true, A0, B0, 0,  0, 0, 0);
    STAGE(true, A0, B0, 0,  1, 0, 0);
    STAGE(true, A0, B0, 0,  0, 1, 0);
    STAGE(true, A0, B0, 0,  1, 1, 0);
    STAGE(true, A0, B0, 64, 0, 1, 1);
    STAGE(true, A0, B0, 64, 1, 1, 1);
    asm volatile("s_waitcnt vmcnt(4)" ::: "memory");   // tile0 landed (per-wave)
    BARR;                                              // collect all waves
    RD_A(a0f, 0, 0);
    RD_B(bf, 0, 0);

    for (int t = 0; t < NT; ++t) {
        const int buf = t & 1, bufn = buf ^ 1;
        if (MODE == 2 && t == 2 * tpp) {
            #pragma unroll
            for (int m = 0; m < 8; ++m)
                #pragma unroll
                for (int n = 0; n < 4; ++n)
                    acc[m][n] *= (1.0f / 2048.0f);
        }
        const int ts1 = t + 1, ts2 = t + 2;
        const bool ok1 = ts1 < NT, ok2 = ts2 < NT;
        const _Float16 *pA1 = A0, *pB1 = B0, *pA2 = A0, *pB2 = B0;
        int kt1 = 0, kt2 = 0;
        if (MODE == 2) {
            if (ok1) { int ps = ts1 / tpp; kt1 = (ts1 - ps * tpp) << 6;
                       pA1 = ps == 0 ? A0 : (ps == 1 ? A1 : A2);
                       pB1 = ps == 0 ? B0 : (ps == 1 ? B1 : B2); }
            if (ok2) { int ps = ts2 / tpp; kt2 = (ts2 - ps * tpp) << 6;
                       pA2 = ps == 0 ? A0 : (ps == 1 ? A1 : A2);
                       pB2 = ps == 0 ? B0 : (ps == 1 ? B1 : B2); }
        } else { kt1 = ts1 << 6; kt2 = ts2 << 6; }

        // ph0: quad m0n0 (a0f, bf=Bh0(t)); read Ah1(t); stage Ah0(t+1)->buf^1
        STAGE(ok1, pA1, pB1, kt1, 0, 0, bufn);
        BARR;
        RD_A(a1f, 1, buf);
        QUADM(a0f, bf, 0, 0);

        // ph1: quad m1n0 (a1f, bf=Bh0(t)); then read Bh1(t) into bf; stage Bh0(t+1)
        STAGE(ok1, pA1, pB1, kt1, 1, 0, bufn);
        BARR;
        QUADM(a1f, bf, 1, 0);
        RD_B(bf, 1, buf);

        // ph2: quad m1n1 (a1f, bf=Bh1(t)); stage Ah1(t+2)->buf
        STAGE(ok2, pA2, pB2, kt2, 0, 1, buf);
        BARR;
        QUADM(a1f, bf, 1, 1);

        // ph3: quad m0n1 (a0f, bf=Bh1(t)); stage Bh1(t+2)->buf;
        // vmcnt publishes tile t+1 before the collecting barrier; tail-read t+1
        STAGE(ok2, pA2, pB2, kt2, 1, 1, buf);
        if (ok2) asm volatile("s_waitcnt vmcnt(4)" ::: "memory");
        else     asm volatile("s_waitcnt vmcnt(0)" ::: "memory");
        BARR;
        QUADM(a0f, bf, 0, 1);
        if (ok1) { RD_A(a0f, 0, bufn); RD_B(bf, 0, bufn); }
    }

    // epilogue; C/D layout: col = lane&15, row = (lane>>4)*4 + reg
    const int r0 = bm * 256 + wr * 64 + (lane >> 4) * 4;
    const int c0 = bn * 256 + wc * 32 + (lane & 15);
    #pragma unroll
    for (int mf = 0; mf < 8; ++mf) {
        const int row = r0 + (mf >> 2) * 128 + (mf & 3) * 16;
        #pragma unroll
        for (int nf = 0; nf < 4; ++nf) {
            const int col = c0 + (nf >> 1) * 128 + (nf & 1) * 16;
            #pragma unroll
            for (int rr = 0; rr < 4; ++rr) {
                const size_t idx = (size_t)(row + rr) * N + col;
                if (MODE == 1) {
                    float g = (float)GP[idx];
                    GP[idx] = (_Float16)(g * acc[mf][nf][rr]);
                } else {
                    Cf[idx] = acc[mf][nf][rr];
                }
            }
        }
    }
}

// ---------------- exact K-th largest |gate| per token + fused mask write ----------------

__global__ __launch_bounds__(256) void topk_mask(const float* __restrict__ gate,
                                                 _Float16* __restrict__ gm) {
    __shared__ unsigned keys[IDIM];
    __shared__ unsigned hist[256];
    __shared__ unsigned sA[256], sB[256];
    __shared__ unsigned selBin, selAbove;

    const int tid = threadIdx.x;
    const int t = blockIdx.x;
    const float* row = gate + (size_t)t * IDIM;

    for (int j = tid; j < IDIM; j += 256)
        keys[j] = __float_as_uint(fabsf(row[j]));
    __syncthreads();

    unsigned prefix = 0;
    int Krem = KKEEP;
    for (int pass = 0; pass < 4; ++pass) {
        const int shift = 24 - 8 * pass;
        hist[tid] = 0;
        __syncthreads();
        for (int j = tid; j < IDIM; j += 256) {
            unsigned k = keys[j];
            bool ok = (pass == 0) || (((k ^ prefix) >> (shift + 8)) == 0u);
            if (ok) atomicAdd(&hist[(k >> shift) & 255u], 1u);
        }
        __syncthreads();
        sA[tid] = hist[tid];
        __syncthreads();
        unsigned* src = sA; unsigned* dst = sB;
        for (int off = 1; off < 256; off <<= 1) {
            unsigned v = src[tid] + ((tid + off < 256) ? src[tid + off] : 0u);
            dst[tid] = v;
            __syncthreads();
            unsigned* tmp = src; src = dst; dst = tmp;
        }
        unsigned S  = src[tid];
        unsigned Sn = (tid < 255) ? src[tid + 1] : 0u;
        if ((int)S >= Krem && (int)Sn < Krem) { selBin = (unsigned)tid; selAbove = Sn; }
        __syncthreads();
        prefix |= (selBin << shift);
        Krem -= (int)selAbove;
        __syncthreads();
    }
    const float kthv = __uint_as_float(prefix);
    _Float16* g16 = gm + (size_t)t * IDIM;
    for (int j = tid; j < IDIM; j += 256) {
        float g = row[j];
        g16[j] = (fabsf(g) >= kthv) ? (_Float16)g : (_Float16)0.0f;
    }
}

// ---------------- host ----------------

extern "C" void kernel_launch(void* const* d_in, const int* in_sizes, int n_in,
                              void* d_out, int out_size, void* d_ws, size_t ws_size,
                              hipStream_t stream) {
    const float* x  = (const float*)d_in[0];   // [T,H]
    const float* Wg = (const float*)d_in[1];   // [I,H]
    const float* Wu = (const float*)d_in[2];   // [I,H]
    const float* Wd = (const float*)d_in[3];   // [H,I]

    const size_t NE   = (size_t)T_TOK * HDIM;
    const size_t szH2 = NE * 2;                          // 33.55 MB

    char* ws = (char*)d_ws;
    _Float16* xh    = (_Float16*)ws;
    _Float16* Wb    = (_Float16*)(ws + szH2);            // Wgh, later Wu16
    _Float16* Wc    = (_Float16*)(ws + 2 * szH2);        // Wgl2, later Wd16
    _Float16* gmask = (_Float16*)(ws + 3 * szH2);        // masked gate f16 -> P (in place)
    _Float16* xl2   = gmask + (size_t)6144 * IDIM;       // parked; consumed before overwritten
    float* gate = (float*)d_out;                         // 2048-token f32 gate chunk

    const long n4 = (long)(NE / 4);
    cast_split<<<1024, 256, 0, stream>>>((const float4*)x,  (ushort4*)xh, (ushort4*)xl2, n4);
    cast_split<<<1024, 256, 0, stream>>>((const float4*)Wg, (ushort4*)Wb, (ushort4*)Wc,  n4);

    // gate phase: fused 3-pass split-f16 GEMM:
    // acc = xl2@Wgh + xh@Wgl2; acc *= 2^-11; acc += xh@Wgh
    for (int c0 = 0; c0 < T_TOK; c0 += 2048) {
        const _Float16* xh_c  = xh  + (size_t)c0 * HDIM;
        const _Float16* xl2_c = xl2 + (size_t)c0 * HDIM;
        gemm8<2><<<dim3(2048 / 256, IDIM / 256), 512, 0, stream>>>(
            xl2_c, Wb, xh_c, Wc, xh_c, Wb, IDIM, HDIM, gate, nullptr);
        topk_mask<<<2048, 256, 0, stream>>>(gate, gmask + (size_t)c0 * IDIM);
    }

    // re-cast weight slots for UP / DOWN
    cast_f16<<<1024, 256, 0, stream>>>((const float4*)Wu, (ushort4*)Wb, n4);
    cast_f16<<<1024, 256, 0, stream>>>((const float4*)Wd, (ushort4*)Wc, n4);

    // UP: in-place P = gmask * (xh @ Wu^T)
    gemm8<1><<<dim3(T_TOK / 256, IDIM / 256), 512, 0, stream>>>(
        xh, Wb, nullptr, nullptr, nullptr, nullptr, IDIM, HDIM, nullptr, gmask);

    // DOWN: out = P @ Wd^T
    gemm8<0><<<dim3(T_TOK / 256, HDIM / 256), 512, 0, stream>>>(
        (const _Float16*)gmask, Wc, nullptr, nullptr, nullptr, nullptr,
        HDIM, IDIM, (float*)d_out, nullptr);
}